// Round 5
// baseline (385.328 us; speedup 1.0000x reference)
//
#include <hip/hip_runtime.h>
#include <math.h>

typedef _Float16 f16;
typedef __attribute__((ext_vector_type(8))) _Float16 f16x8;
typedef __attribute__((ext_vector_type(4))) float    f32x4;
typedef __attribute__((address_space(3))) unsigned int       as3u32;
typedef const __attribute__((address_space(1))) unsigned int as1u32;

constexpr int NB=16, NT=512, NF=256, NMIC=4, NELE=37, NAZI=73;
constexpr int MROWS = NB*NT;     // 8192
constexpr int KDIM  = NF*NMIC;   // 1024
constexpr int NCAND = NELE*NAZI; // 2701
constexpr int NPAD  = 2816;      // padded candidate rows (22*128, also 11*256)
constexpr float SCALE = 2.0f / (float)KDIM;

constexpr size_t align256(size_t x){ return (x + 255) & ~(size_t)255; }
constexpr size_t G_BYTES = (size_t)NCAND*NCAND*4;          // 29.18 MB
constexpr size_t A2_OFF  = align256(G_BYTES);
constexpr size_t A2_BYTES = (size_t)MROWS*2048*2;          // 33.55 MB (interleaved limbs)
constexpr size_t B2_OFF  = A2_OFF + A2_BYTES;
constexpr size_t B2_BYTES = (size_t)NPAD*2048*2;           // 11.53 MB
constexpr size_t WS_FAST = B2_OFF + B2_BYTES;              // ~74.3 MB
constexpr size_t WS_FB   = G_BYTES;

// ---------- pre-pass: split f32 -> interleaved limbs [row][kt(32)][hi 32 f16 | lo 32 f16] ----------
__global__ __launch_bounds__(256)
void split_interleave(const float* __restrict__ src, f16* __restrict__ dst,
                      int nrows_src, int nrows_tot)
{
    int gid = blockIdx.x*256 + threadIdx.x;   // one 8-elem granule
    int m  = gid >> 7;                        // 128 granules per row (1024 k / 8)
    int gi = gid & 127;
    if (m >= nrows_tot) return;
    int kt = gi >> 2, wg = gi & 3;
    long so  = (long)m*1024 + kt*32 + wg*8;
    long dof = (long)m*2048 + kt*64 + wg*8;
    f16x8 h, l;
    if (m < nrows_src) {
        float4 x0 = *(const float4*)(src + so);
        float4 x1 = *(const float4*)(src + so + 4);
        float xs[8] = {x0.x,x0.y,x0.z,x0.w,x1.x,x1.y,x1.z,x1.w};
        #pragma unroll
        for (int j=0;j<8;++j){
            f16 hh = (f16)xs[j];
            l[j] = (f16)((xs[j] - (float)hh)*2048.0f);
            h[j] = hh;
        }
    } else {
        #pragma unroll
        for (int j=0;j<8;++j){ h[j]=(f16)0.0f; l[j]=(f16)0.0f; }
    }
    *(f16x8*)(dst + dof)      = h;
    *(f16x8*)(dst + dof + 32) = l;
}

// ---------- limb-GEMM: C[M,N] = (A*B^T)*scale via 3-term f16 MFMA ----------
// Tile 256x128, BK=32 (one interleaved k-tile = 64 f16/row), 8 waves (2M x 4N),
// triple-buffered LDS, counted vmcnt(6), one raw barrier per K-tile.
// MODE 0: rectangular grid (gx=N/128, gy=M/256) + XCD swizzle.
// MODE 1: symmetric (Gram): 1D triangular grid, mirror writes.
template<int MODE>
__global__ __launch_bounds__(512, 2)
void gemm_limb(const f16* __restrict__ A2, const f16* __restrict__ B2,
               float* __restrict__ C, int M, int N, float scale)
{
    __shared__ f16 ldsA[3][256*64];   // 3 x 32 KB
    __shared__ f16 ldsB[3][128*64];   // 3 x 16 KB   (total 144 KB)

    const int tid  = threadIdx.x;
    const int wid  = tid >> 6;
    const int lane = tid & 63;
    const int wr   = wid >> 2;   // 0..1
    const int wc   = wid & 3;    // 0..3

    int row0, col0;
    if (MODE == 0) {
        int gx = gridDim.x, nwg = gx*gridDim.y;
        int orig = blockIdx.x + gx*blockIdx.y;
        int wg = orig;
        if ((nwg & 7) == 0) wg = (orig&7)*(nwg>>3) + (orig>>3);
        row0 = (wg / gx) * 256;
        col0 = (wg % gx) * 128;
    } else {
        int t = blockIdx.x, i = 0;
        #pragma unroll 1
        for (; i < 11; ++i){ int cnt = 22 - 2*i; if (t < cnt) break; t -= cnt; }
        row0 = i * 256;
        col0 = (2*i + t) * 128;
    }

    // staging lane geometry (chunk = 8 rows x 128 B = 1024 B per wave-call)
    const int lr8 = lane >> 3;        // row within chunk
    const int lg  = lane & 7;         // dest granule
    const int sg  = lg ^ lr8;         // pre-swizzled source granule

    // ds_read offsets (f16 units), XOR-swizzled: slot = g ^ (row&7)
    int aof[8], alf[8], bof[2], blf[2];
    #pragma unroll
    for (int fi=0; fi<8; ++fi){
        int ra = wr*128 + fi*16 + (lane&15);
        int g  = lane>>4;
        aof[fi] = ra*64 + ((g     ^ (ra&7))*8);
        alf[fi] = ra*64 + (((4+g) ^ (ra&7))*8);
    }
    #pragma unroll
    for (int fj=0; fj<2; ++fj){
        int rb = wc*32 + fj*16 + (lane&15);
        int g  = lane>>4;
        bof[fj] = rb*64 + ((g     ^ (rb&7))*8);
        blf[fj] = rb*64 + (((4+g) ^ (rb&7))*8);
    }

    f32x4 acc0[8][2], acc1[8][2];
    #pragma unroll
    for (int i=0;i<8;++i)
        #pragma unroll
        for (int j=0;j<2;++j){
            acc0[i][j] = (f32x4){0.f,0.f,0.f,0.f};
            acc1[i][j] = (f32x4){0.f,0.f,0.f,0.f};
        }

    #define STAGE_A(buf, kt, q) do {                                          \
        int c_ = (q)*8 + wid;                                                 \
        long so_ = (long)(row0 + c_*8 + lr8)*2048 + (long)(kt)*64 + sg*8;     \
        __builtin_amdgcn_global_load_lds((as1u32*)(A2 + so_),                 \
            (as3u32*)(&ldsA[buf][c_*512]), 16, 0, 0);                         \
    } while(0)
    #define STAGE_B(buf, kt, q) do {                                          \
        int c_ = (q)*8 + wid;                                                 \
        long so_ = (long)(col0 + c_*8 + lr8)*2048 + (long)(kt)*64 + sg*8;     \
        __builtin_amdgcn_global_load_lds((as1u32*)(B2 + so_),                 \
            (as3u32*)(&ldsB[buf][c_*512]), 16, 0, 0);                         \
    } while(0)

    // prologue: stage tiles 0 and 1 (6 loads each, in order)
    STAGE_A(0,0,0); STAGE_A(0,0,1); STAGE_A(0,0,2); STAGE_A(0,0,3);
    STAGE_B(0,0,0); STAGE_B(0,0,1);
    STAGE_A(1,1,0); STAGE_A(1,1,1); STAGE_A(1,1,2); STAGE_A(1,1,3);
    STAGE_B(1,1,0); STAGE_B(1,1,1);
    asm volatile("s_waitcnt vmcnt(6)" ::: "memory");   // tile0 landed
    __builtin_amdgcn_s_barrier();
    asm volatile("" ::: "memory");

    const int nt = KDIM/32;   // 32
    #pragma unroll 1
    for (int t = 0; t < nt; ++t) {
        const f16* At = ldsA[t % 3];
        const f16* Bt = ldsB[t % 3];
        const int  nb = (t + 2) % 3;
        const bool doStage = (t + 2) < nt;

        f16x8 ah[8], al[8], bh[2], bl[2];

        // ---- Phase 1: stage A(q0,q1) of t+2 ; read ah[0..3], bh ; hh MFMA (ai 0..3)
        if (doStage){ STAGE_A(nb, t+2, 0); STAGE_A(nb, t+2, 1); }
        #pragma unroll
        for (int fi=0; fi<4; ++fi) ah[fi] = *(const f16x8*)(At + aof[fi]);
        #pragma unroll
        for (int fj=0; fj<2; ++fj) bh[fj] = *(const f16x8*)(Bt + bof[fj]);
        __builtin_amdgcn_s_setprio(1);
        #pragma unroll
        for (int fi=0; fi<4; ++fi)
            #pragma unroll
            for (int fj=0; fj<2; ++fj)
                acc0[fi][fj] = __builtin_amdgcn_mfma_f32_16x16x32_f16(ah[fi], bh[fj], acc0[fi][fj], 0,0,0);
        __builtin_amdgcn_s_setprio(0);

        // ---- Phase 2: stage A(q2,q3) ; read al[0..3], bl ; cross MFMA (ai 0..3)
        if (doStage){ STAGE_A(nb, t+2, 2); STAGE_A(nb, t+2, 3); }
        #pragma unroll
        for (int fi=0; fi<4; ++fi) al[fi] = *(const f16x8*)(At + alf[fi]);
        #pragma unroll
        for (int fj=0; fj<2; ++fj) bl[fj] = *(const f16x8*)(Bt + blf[fj]);
        __builtin_amdgcn_s_setprio(1);
        #pragma unroll
        for (int fi=0; fi<4; ++fi)
            #pragma unroll
            for (int fj=0; fj<2; ++fj){
                acc1[fi][fj] = __builtin_amdgcn_mfma_f32_16x16x32_f16(ah[fi], bl[fj], acc1[fi][fj], 0,0,0);
                acc1[fi][fj] = __builtin_amdgcn_mfma_f32_16x16x32_f16(al[fi], bh[fj], acc1[fi][fj], 0,0,0);
            }
        __builtin_amdgcn_s_setprio(0);

        // ---- Phase 3: stage B(q0) ; read ah[4..7] ; hh MFMA (ai 4..7)
        if (doStage){ STAGE_B(nb, t+2, 0); }
        #pragma unroll
        for (int fi=4; fi<8; ++fi) ah[fi] = *(const f16x8*)(At + aof[fi]);
        __builtin_amdgcn_s_setprio(1);
        #pragma unroll
        for (int fi=4; fi<8; ++fi)
            #pragma unroll
            for (int fj=0; fj<2; ++fj)
                acc0[fi][fj] = __builtin_amdgcn_mfma_f32_16x16x32_f16(ah[fi], bh[fj], acc0[fi][fj], 0,0,0);
        __builtin_amdgcn_s_setprio(0);

        // ---- Phase 4: stage B(q1) ; read al[4..7] ; cross MFMA (ai 4..7)
        if (doStage){ STAGE_B(nb, t+2, 1); }
        #pragma unroll
        for (int fi=4; fi<8; ++fi) al[fi] = *(const f16x8*)(At + alf[fi]);
        __builtin_amdgcn_s_setprio(1);
        #pragma unroll
        for (int fi=4; fi<8; ++fi)
            #pragma unroll
            for (int fj=0; fj<2; ++fj){
                acc1[fi][fj] = __builtin_amdgcn_mfma_f32_16x16x32_f16(ah[fi], bl[fj], acc1[fi][fj], 0,0,0);
                acc1[fi][fj] = __builtin_amdgcn_mfma_f32_16x16x32_f16(al[fi], bh[fj], acc1[fi][fj], 0,0,0);
            }
        __builtin_amdgcn_s_setprio(0);

        // ---- tile boundary: counted wait (never 0 until drain), raw barrier
        if (doStage) asm volatile("s_waitcnt vmcnt(6)" ::: "memory");
        else         asm volatile("s_waitcnt vmcnt(0)" ::: "memory");
        __builtin_amdgcn_s_barrier();
        asm volatile("" ::: "memory");
    }
    #undef STAGE_A
    #undef STAGE_B

    // epilogue: C/D layout col=lane&15, row=(lane>>4)*4+e
    const float inv2048 = 1.0f/2048.0f;
    #pragma unroll
    for (int fi=0; fi<8; ++fi){
        #pragma unroll
        for (int fj=0; fj<2; ++fj){
            int c = col0 + wc*32 + fj*16 + (lane & 15);
            #pragma unroll
            for (int e=0; e<4; ++e){
                int r = row0 + wr*128 + fi*16 + (lane >> 4)*4 + e;
                float v = (acc0[fi][fj][e] + acc1[fi][fj][e]*inv2048)*scale;
                if (r < M && c < N){
                    C[(size_t)r*N + c] = v;
                    if (MODE == 1) C[(size_t)c*N + r] = v;
                }
            }
        }
    }
}

// ---------- fallback f32 SGEMM (round-1, known-good) ----------
#define TILE 64
#define BKK  16
#define LDSP 68
__global__ __launch_bounds__(256)
void sgemm_nt_kernel(const float* __restrict__ A, const float* __restrict__ B,
                     float* __restrict__ C, int M, int N, float scale)
{
    __shared__ __align__(16) float As[BKK][LDSP];
    __shared__ __align__(16) float Bs[BKK][LDSP];
    const int tid = threadIdx.x;
    const int tx = tid & 15, ty = tid >> 4;
    const int row0 = blockIdx.y*TILE, col0 = blockIdx.x*TILE;
    const int lm = tid >> 2, lk0 = (tid & 3)*4;
    const int ar = row0 + lm, br = col0 + lm;
    const bool av = (ar < M), bv = (br < N);
    const float* aptr = A + (size_t)(av ? ar : 0)*KDIM + lk0;
    const float* bptr = B + (size_t)(bv ? br : 0)*KDIM + lk0;
    float acc[4][4] = {};
    for (int k0 = 0; k0 < KDIM; k0 += BKK) {
        float4 a4 = av ? *(const float4*)(aptr + k0) : make_float4(0,0,0,0);
        float4 b4 = bv ? *(const float4*)(bptr + k0) : make_float4(0,0,0,0);
        __syncthreads();
        As[lk0+0][lm]=a4.x; As[lk0+1][lm]=a4.y; As[lk0+2][lm]=a4.z; As[lk0+3][lm]=a4.w;
        Bs[lk0+0][lm]=b4.x; Bs[lk0+1][lm]=b4.y; Bs[lk0+2][lm]=b4.z; Bs[lk0+3][lm]=b4.w;
        __syncthreads();
        #pragma unroll
        for (int k=0;k<BKK;++k){
            float4 av4 = *(const float4*)(&As[k][ty*4]);
            float4 bv4 = *(const float4*)(&Bs[k][tx*4]);
            float am[4]={av4.x,av4.y,av4.z,av4.w};
            float bm[4]={bv4.x,bv4.y,bv4.z,bv4.w};
            #pragma unroll
            for (int i=0;i<4;++i)
                #pragma unroll
                for (int j=0;j<4;++j)
                    acc[i][j] = fmaf(am[i], bm[j], acc[i][j]);
        }
    }
    #pragma unroll
    for (int i=0;i<4;++i){
        int r = row0 + ty*4 + i;
        if (r >= M) continue;
        #pragma unroll
        for (int j=0;j<4;++j){
            int c = col0 + tx*4 + j;
            if (c < N) C[(size_t)r*N + c] = acc[i][j]*scale;
        }
    }
}

// ---------- fused IDL argmax: both iterations, ss row kept in registers ----------
__global__ __launch_bounds__(256)
void argmax_fused(const float* __restrict__ ss, const float* __restrict__ G,
                  const float* __restrict__ ele_c, const float* __restrict__ azi_c,
                  float* __restrict__ out_doa, float* __restrict__ out_vad)
{
    const int row  = blockIdx.x*4 + (threadIdx.x >> 6);
    const int lane = threadIdx.x & 63;
    const float* srow = ss + (size_t)row*NCAND;

    float s[43];
    #pragma unroll
    for (int i=0;i<43;++i){
        int c = i*64 + lane;
        s[i] = (c < NCAND) ? srow[c] : -1e30f;
    }

    // ---- iteration 1
    float best = -1e30f; int bi = 0x7fffffff;
    #pragma unroll
    for (int i=0;i<43;++i){
        int c = i*64 + lane;
        if (s[i] > best){ best = s[i]; bi = c; }
    }
    #pragma unroll
    for (int off=32; off; off>>=1){
        float v2 = __shfl_xor(best, off);
        int   i2 = __shfl_xor(bi, off);
        if (v2 > best || (v2 == best && i2 < bi)){ best = v2; bi = i2; }
    }
    float den   = G[(size_t)bi*NCAND + bi];
    float ratio = best / (SCALE*den);
    if (lane == 0){
        int ei = bi / NAZI, ai = bi - ei*NAZI;
        out_doa[(size_t)row*4 + 0] = ele_c[ei];
        out_doa[(size_t)row*4 + 2] = azi_c[ai];
        out_vad[(size_t)row*2 + 0] = ratio;
    }

    // ---- iteration 2: scores2 = s - ratio*SCALE*G[bi, :]
    const float rs = ratio*SCALE;
    const float* grow = G + (size_t)bi*NCAND;
    float best2 = -1e30f; int b2 = 0x7fffffff;
    #pragma unroll
    for (int i=0;i<43;++i){
        int c = i*64 + lane;
        float v = (c < NCAND) ? fmaf(-rs, grow[c], s[i]) : -1e30f;
        if (v > best2){ best2 = v; b2 = c; }
    }
    #pragma unroll
    for (int off=32; off; off>>=1){
        float v2 = __shfl_xor(best2, off);
        int   i2 = __shfl_xor(b2, off);
        if (v2 > best2 || (v2 == best2 && i2 < b2)){ best2 = v2; b2 = i2; }
    }
    if (lane == 0){
        float den2   = G[(size_t)b2*NCAND + b2];
        float ratio2 = best2 / (SCALE*den2);
        int ei = b2 / NAZI, ai = b2 - ei*NAZI;
        out_doa[(size_t)row*4 + 1] = ele_c[ei];
        out_doa[(size_t)row*4 + 3] = azi_c[ai];
        out_vad[(size_t)row*2 + 1] = ratio2;
    }
}

// ---------- launch ----------
extern "C" void kernel_launch(void* const* d_in, const int* in_sizes, int n_in,
                              void* d_out, int out_size, void* d_ws, size_t ws_size,
                              hipStream_t stream)
{
    const float* ipd   = (const float*)d_in[0];   // [8192,1024]
    const float* tmpl  = (const float*)d_in[1];   // [2701,1024]
    const float* ele_c = (const float*)d_in[2];
    const float* azi_c = (const float*)d_in[3];

    float* out     = (float*)d_out;
    float* out_doa = out;                                       // [8192,2,2]
    float* out_vad = out + (size_t)MROWS*4;                     // [8192,2]
    float* out_ss  = out + (size_t)MROWS*4 + (size_t)MROWS*2;   // [8192,2701]

    char*  ws = (char*)d_ws;
    float* G  = (float*)ws;

    dim3 blk256(256);

    if (ws_size >= WS_FAST) {
        f16* A2 = (f16*)(ws + A2_OFF);
        f16* B2 = (f16*)(ws + B2_OFF);

        hipLaunchKernelGGL(split_interleave, dim3(MROWS*128/256), blk256, 0, stream,
                           ipd, A2, MROWS, MROWS);
        hipLaunchKernelGGL(split_interleave, dim3(NPAD*128/256), blk256, 0, stream,
                           tmpl, B2, NCAND, NPAD);

        // pred_ss: [8192 x 2701]
        hipLaunchKernelGGL((gemm_limb<0>), dim3(22, 32), dim3(512), 0, stream,
                           A2, B2, out_ss, MROWS, NCAND, SCALE);
        // Gram (symmetric, triangular grid): [2701 x 2701]
        hipLaunchKernelGGL((gemm_limb<1>), dim3(132), dim3(512), 0, stream,
                           B2, B2, G, NCAND, NCAND, 1.0f);
    } else {
        dim3 g1((NCAND + TILE - 1)/TILE, MROWS/TILE);
        hipLaunchKernelGGL(sgemm_nt_kernel, g1, blk256, 0, stream,
                           ipd, tmpl, out_ss, MROWS, NCAND, SCALE);
        dim3 g2((NCAND + TILE - 1)/TILE, (NCAND + TILE - 1)/TILE);
        hipLaunchKernelGGL(sgemm_nt_kernel, g2, blk256, 0, stream,
                           tmpl, tmpl, G, NCAND, NCAND, 1.0f);
    }

    hipLaunchKernelGGL(argmax_fused, dim3(MROWS/4), blk256, 0, stream,
                       out_ss, G, ele_c, azi_c, out_doa, out_vad);
}

// Round 6
// 359.446 us; speedup vs baseline: 1.0720x; 1.0720x over previous
//
#include <hip/hip_runtime.h>
#include <math.h>

typedef _Float16 f16;
typedef __attribute__((ext_vector_type(8))) _Float16 f16x8;
typedef __attribute__((ext_vector_type(4))) float    f32x4;
typedef __attribute__((address_space(3))) unsigned int       as3u32;
typedef const __attribute__((address_space(1))) unsigned int as1u32;

constexpr int NB=16, NT=512, NF=256, NMIC=4, NELE=37, NAZI=73;
constexpr int MROWS = NB*NT;     // 8192
constexpr int KDIM  = NF*NMIC;   // 1024
constexpr int NCAND = NELE*NAZI; // 2701
constexpr int NPAD  = 2816;      // padded candidate rows (22*128)
constexpr float SCALE = 2.0f / (float)KDIM;

constexpr size_t align256(size_t x){ return (x + 255) & ~(size_t)255; }
constexpr size_t G_BYTES = (size_t)NCAND*NCAND*4;          // 29.18 MB
constexpr size_t A2_OFF  = align256(G_BYTES);
constexpr size_t A2_BYTES = (size_t)MROWS*2048*2;          // 33.55 MB (interleaved limbs)
constexpr size_t B2_OFF  = A2_OFF + A2_BYTES;
constexpr size_t B2_BYTES = (size_t)NPAD*2048*2;           // 11.53 MB
constexpr size_t WS_FAST = B2_OFF + B2_BYTES;              // ~74.3 MB

// ---------- pre-pass: split f32 -> interleaved limbs [row][kt(32)][hi 32 f16 | lo 32 f16] ----------
__global__ __launch_bounds__(256)
void split_interleave(const float* __restrict__ src, f16* __restrict__ dst,
                      int nrows_src, int nrows_tot)
{
    int gid = blockIdx.x*256 + threadIdx.x;   // one 8-elem granule
    int m  = gid >> 7;                        // 128 granules per row (1024 k / 8)
    int gi = gid & 127;
    if (m >= nrows_tot) return;
    int kt = gi >> 2, wg = gi & 3;
    long so  = (long)m*1024 + kt*32 + wg*8;
    long dof = (long)m*2048 + kt*64 + wg*8;
    f16x8 h, l;
    if (m < nrows_src) {
        float4 x0 = *(const float4*)(src + so);
        float4 x1 = *(const float4*)(src + so + 4);
        float xs[8] = {x0.x,x0.y,x0.z,x0.w,x1.x,x1.y,x1.z,x1.w};
        #pragma unroll
        for (int j=0;j<8;++j){
            f16 hh = (f16)xs[j];
            l[j] = (f16)((xs[j] - (float)hh)*2048.0f);
            h[j] = hh;
        }
    } else {
        #pragma unroll
        for (int j=0;j<8;++j){ h[j]=(f16)0.0f; l[j]=(f16)0.0f; }
    }
    *(f16x8*)(dst + dof)      = h;
    *(f16x8*)(dst + dof + 32) = l;
}

// ---------- limb-GEMM: C[M,N] = (A*B^T)*scale via 3-term f16 MFMA ----------
// Tile 256x128, BK=32 f32-k (interleaved k-tile = 64 f16/row), 8 waves (2M x 4N),
// triple-buffered LDS, 2-tile prefetch, m201-style per-phase barrier pairs:
//   {ds_read subtile || issue stage} -> barrier -> lgkmcnt(0) -> setprio(1) ->
//   MFMA cluster -> setprio(0) -> barrier     (4 phases/tile, vmcnt(6) once/tile)
template<int MODE>
__global__ __launch_bounds__(512, 2)
void gemm_limb(const f16* __restrict__ A2, const f16* __restrict__ B2,
               float* __restrict__ C, int M, int N, float scale)
{
    __shared__ f16 ldsA[3][256*64];   // 3 x 32 KB
    __shared__ f16 ldsB[3][128*64];   // 3 x 16 KB   (total 144 KB)

    const int tid  = threadIdx.x;
    const int wid  = tid >> 6;
    const int lane = tid & 63;
    const int wr   = wid >> 2;   // 0..1
    const int wc   = wid & 3;    // 0..3

    int row0, col0;
    if (MODE == 0) {
        int gx = gridDim.x, nwg = gx*gridDim.y;
        int orig = blockIdx.x + gx*blockIdx.y;
        int wg = orig;
        if ((nwg & 7) == 0) wg = (orig&7)*(nwg>>3) + (orig>>3);
        row0 = (wg / gx) * 256;
        col0 = (wg % gx) * 128;
    } else {
        int t = blockIdx.x, i = 0;
        #pragma unroll 1
        for (; i < 11; ++i){ int cnt = 22 - 2*i; if (t < cnt) break; t -= cnt; }
        row0 = i * 256;
        col0 = (2*i + t) * 128;
    }

    // staging lane geometry (chunk = 8 rows x 128 B = 1024 B per wave-call)
    const int lr8 = lane >> 3;        // row within chunk
    const int lg  = lane & 7;         // dest granule
    const int sg  = lg ^ lr8;         // pre-swizzled source granule

    // ds_read offsets (f16 units), XOR-swizzled: slot = g ^ (row&7)
    int aof[8], alf[8], bof[2], blf[2];
    #pragma unroll
    for (int fi=0; fi<8; ++fi){
        int ra = wr*128 + fi*16 + (lane&15);
        int g  = lane>>4;
        aof[fi] = ra*64 + ((g     ^ (ra&7))*8);
        alf[fi] = ra*64 + (((4+g) ^ (ra&7))*8);
    }
    #pragma unroll
    for (int fj=0; fj<2; ++fj){
        int rb = wc*32 + fj*16 + (lane&15);
        int g  = lane>>4;
        bof[fj] = rb*64 + ((g     ^ (rb&7))*8);
        blf[fj] = rb*64 + (((4+g) ^ (rb&7))*8);
    }

    f32x4 acc0[8][2], acc1[8][2];
    #pragma unroll
    for (int i=0;i<8;++i)
        #pragma unroll
        for (int j=0;j<2;++j){
            acc0[i][j] = (f32x4){0.f,0.f,0.f,0.f};
            acc1[i][j] = (f32x4){0.f,0.f,0.f,0.f};
        }

    #define STAGE_A(buf, kt, q) do {                                          \
        int c_ = (q)*8 + wid;                                                 \
        long so_ = (long)(row0 + c_*8 + lr8)*2048 + (long)(kt)*64 + sg*8;     \
        __builtin_amdgcn_global_load_lds((as1u32*)(A2 + so_),                 \
            (as3u32*)(&ldsA[buf][c_*512]), 16, 0, 0);                         \
    } while(0)
    #define STAGE_B(buf, kt, q) do {                                          \
        int c_ = (q)*8 + wid;                                                 \
        long so_ = (long)(col0 + c_*8 + lr8)*2048 + (long)(kt)*64 + sg*8;     \
        __builtin_amdgcn_global_load_lds((as1u32*)(B2 + so_),                 \
            (as3u32*)(&ldsB[buf][c_*512]), 16, 0, 0);                         \
    } while(0)

    // prologue: stage tiles 0 and 1 (6 loads each, in order)
    STAGE_A(0,0,0); STAGE_A(0,0,1); STAGE_A(0,0,2); STAGE_A(0,0,3);
    STAGE_B(0,0,0); STAGE_B(0,0,1);
    STAGE_A(1,1,0); STAGE_A(1,1,1); STAGE_A(1,1,2); STAGE_A(1,1,3);
    STAGE_B(1,1,0); STAGE_B(1,1,1);
    asm volatile("s_waitcnt vmcnt(6)" ::: "memory");   // tile0 landed
    __builtin_amdgcn_s_barrier();
    asm volatile("" ::: "memory");

    const int nt = KDIM/32;   // 32
    #pragma unroll 1
    for (int t = 0; t < nt; ++t) {
        const f16* At = ldsA[t % 3];
        const f16* Bt = ldsB[t % 3];
        const int  nb = (t + 2) % 3;
        const bool doStage = (t + 2) < nt;

        f16x8 ah[8], al[8], bh[2], bl[2];

        // ---- Phase 1: read ah[0..3], bh ; stage A(q0,q1) of t+2 ; hh MFMA (ai 0..3)
        #pragma unroll
        for (int fi=0; fi<4; ++fi) ah[fi] = *(const f16x8*)(At + aof[fi]);
        #pragma unroll
        for (int fj=0; fj<2; ++fj) bh[fj] = *(const f16x8*)(Bt + bof[fj]);
        if (doStage){ STAGE_A(nb, t+2, 0); STAGE_A(nb, t+2, 1); }
        __builtin_amdgcn_s_barrier();
        asm volatile("s_waitcnt lgkmcnt(0)" ::: "memory");
        __builtin_amdgcn_s_setprio(1);
        #pragma unroll
        for (int fi=0; fi<4; ++fi)
            #pragma unroll
            for (int fj=0; fj<2; ++fj)
                acc0[fi][fj] = __builtin_amdgcn_mfma_f32_16x16x32_f16(ah[fi], bh[fj], acc0[fi][fj], 0,0,0);
        __builtin_amdgcn_s_setprio(0);
        __builtin_amdgcn_s_barrier();

        // ---- Phase 2: read al[0..3], bl ; stage A(q2,q3) ; cross MFMA (ai 0..3)
        #pragma unroll
        for (int fi=0; fi<4; ++fi) al[fi] = *(const f16x8*)(At + alf[fi]);
        #pragma unroll
        for (int fj=0; fj<2; ++fj) bl[fj] = *(const f16x8*)(Bt + blf[fj]);
        if (doStage){ STAGE_A(nb, t+2, 2); STAGE_A(nb, t+2, 3); }
        __builtin_amdgcn_s_barrier();
        asm volatile("s_waitcnt lgkmcnt(0)" ::: "memory");
        __builtin_amdgcn_s_setprio(1);
        #pragma unroll
        for (int fi=0; fi<4; ++fi)
            #pragma unroll
            for (int fj=0; fj<2; ++fj){
                acc1[fi][fj] = __builtin_amdgcn_mfma_f32_16x16x32_f16(ah[fi], bl[fj], acc1[fi][fj], 0,0,0);
                acc1[fi][fj] = __builtin_amdgcn_mfma_f32_16x16x32_f16(al[fi], bh[fj], acc1[fi][fj], 0,0,0);
            }
        __builtin_amdgcn_s_setprio(0);
        __builtin_amdgcn_s_barrier();

        // ---- Phase 3: read ah[4..7] ; stage B(q0) ; hh MFMA (ai 4..7)
        #pragma unroll
        for (int fi=4; fi<8; ++fi) ah[fi] = *(const f16x8*)(At + aof[fi]);
        if (doStage){ STAGE_B(nb, t+2, 0); }
        __builtin_amdgcn_s_barrier();
        asm volatile("s_waitcnt lgkmcnt(0)" ::: "memory");
        __builtin_amdgcn_s_setprio(1);
        #pragma unroll
        for (int fi=4; fi<8; ++fi)
            #pragma unroll
            for (int fj=0; fj<2; ++fj)
                acc0[fi][fj] = __builtin_amdgcn_mfma_f32_16x16x32_f16(ah[fi], bh[fj], acc0[fi][fj], 0,0,0);
        __builtin_amdgcn_s_setprio(0);
        __builtin_amdgcn_s_barrier();

        // ---- Phase 4: read al[4..7] ; stage B(q1) ; vmcnt ; cross MFMA (ai 4..7)
        #pragma unroll
        for (int fi=4; fi<8; ++fi) al[fi] = *(const f16x8*)(At + alf[fi]);
        if (doStage){ STAGE_B(nb, t+2, 1); }
        if (doStage) asm volatile("s_waitcnt vmcnt(6)" ::: "memory");
        else         asm volatile("s_waitcnt vmcnt(0)" ::: "memory");
        __builtin_amdgcn_s_barrier();
        asm volatile("s_waitcnt lgkmcnt(0)" ::: "memory");
        __builtin_amdgcn_s_setprio(1);
        #pragma unroll
        for (int fi=4; fi<8; ++fi)
            #pragma unroll
            for (int fj=0; fj<2; ++fj){
                acc1[fi][fj] = __builtin_amdgcn_mfma_f32_16x16x32_f16(ah[fi], bl[fj], acc1[fi][fj], 0,0,0);
                acc1[fi][fj] = __builtin_amdgcn_mfma_f32_16x16x32_f16(al[fi], bh[fj], acc1[fi][fj], 0,0,0);
            }
        __builtin_amdgcn_s_setprio(0);
        __builtin_amdgcn_s_barrier();
    }
    #undef STAGE_A
    #undef STAGE_B

    // epilogue: C/D layout col=lane&15, row=(lane>>4)*4+e
    const float inv2048 = 1.0f/2048.0f;
    #pragma unroll
    for (int fi=0; fi<8; ++fi){
        #pragma unroll
        for (int fj=0; fj<2; ++fj){
            int c = col0 + wc*32 + fj*16 + (lane & 15);
            #pragma unroll
            for (int e=0; e<4; ++e){
                int r = row0 + wr*128 + fi*16 + (lane >> 4)*4 + e;
                float v = (acc0[fi][fj][e] + acc1[fi][fj][e]*inv2048)*scale;
                if (r < M && c < N){
                    C[(size_t)r*N + c] = v;
                    if (MODE == 1) C[(size_t)c*N + r] = v;
                }
            }
        }
    }
}

// ---------- fallback f32 SGEMM (round-1, known-good) ----------
#define TILE 64
#define BKK  16
#define LDSP 68
__global__ __launch_bounds__(256)
void sgemm_nt_kernel(const float* __restrict__ A, const float* __restrict__ B,
                     float* __restrict__ C, int M, int N, float scale)
{
    __shared__ __align__(16) float As[BKK][LDSP];
    __shared__ __align__(16) float Bs[BKK][LDSP];
    const int tid = threadIdx.x;
    const int tx = tid & 15, ty = tid >> 4;
    const int row0 = blockIdx.y*TILE, col0 = blockIdx.x*TILE;
    const int lm = tid >> 2, lk0 = (tid & 3)*4;
    const int ar = row0 + lm, br = col0 + lm;
    const bool av = (ar < M), bv = (br < N);
    const float* aptr = A + (size_t)(av ? ar : 0)*KDIM + lk0;
    const float* bptr = B + (size_t)(bv ? br : 0)*KDIM + lk0;
    float acc[4][4] = {};
    for (int k0 = 0; k0 < KDIM; k0 += BKK) {
        float4 a4 = av ? *(const float4*)(aptr + k0) : make_float4(0,0,0,0);
        float4 b4 = bv ? *(const float4*)(bptr + k0) : make_float4(0,0,0,0);
        __syncthreads();
        As[lk0+0][lm]=a4.x; As[lk0+1][lm]=a4.y; As[lk0+2][lm]=a4.z; As[lk0+3][lm]=a4.w;
        Bs[lk0+0][lm]=b4.x; Bs[lk0+1][lm]=b4.y; Bs[lk0+2][lm]=b4.z; Bs[lk0+3][lm]=b4.w;
        __syncthreads();
        #pragma unroll
        for (int k=0;k<BKK;++k){
            float4 av4 = *(const float4*)(&As[k][ty*4]);
            float4 bv4 = *(const float4*)(&Bs[k][tx*4]);
            float am[4]={av4.x,av4.y,av4.z,av4.w};
            float bm[4]={bv4.x,bv4.y,bv4.z,bv4.w};
            #pragma unroll
            for (int i=0;i<4;++i)
                #pragma unroll
                for (int j=0;j<4;++j)
                    acc[i][j] = fmaf(am[i], bm[j], acc[i][j]);
        }
    }
    #pragma unroll
    for (int i=0;i<4;++i){
        int r = row0 + ty*4 + i;
        if (r >= M) continue;
        #pragma unroll
        for (int j=0;j<4;++j){
            int c = col0 + tx*4 + j;
            if (c < N) C[(size_t)r*N + c] = acc[i][j]*scale;
        }
    }
}

// ---------- fused IDL argmax: both iterations, ss row kept in registers ----------
__global__ __launch_bounds__(256)
void argmax_fused(const float* __restrict__ ss, const float* __restrict__ G,
                  const float* __restrict__ ele_c, const float* __restrict__ azi_c,
                  float* __restrict__ out_doa, float* __restrict__ out_vad)
{
    const int row  = blockIdx.x*4 + (threadIdx.x >> 6);
    const int lane = threadIdx.x & 63;
    const float* srow = ss + (size_t)row*NCAND;

    float s[43];
    #pragma unroll
    for (int i=0;i<43;++i){
        int c = i*64 + lane;
        s[i] = (c < NCAND) ? srow[c] : -1e30f;
    }

    // ---- iteration 1
    float best = -1e30f; int bi = 0x7fffffff;
    #pragma unroll
    for (int i=0;i<43;++i){
        int c = i*64 + lane;
        if (s[i] > best){ best = s[i]; bi = c; }
    }
    #pragma unroll
    for (int off=32; off; off>>=1){
        float v2 = __shfl_xor(best, off);
        int   i2 = __shfl_xor(bi, off);
        if (v2 > best || (v2 == best && i2 < bi)){ best = v2; bi = i2; }
    }
    float den   = G[(size_t)bi*NCAND + bi];
    float ratio = best / (SCALE*den);
    if (lane == 0){
        int ei = bi / NAZI, ai = bi - ei*NAZI;
        out_doa[(size_t)row*4 + 0] = ele_c[ei];
        out_doa[(size_t)row*4 + 2] = azi_c[ai];
        out_vad[(size_t)row*2 + 0] = ratio;
    }

    // ---- iteration 2: scores2 = s - ratio*SCALE*G[bi, :]
    const float rs = ratio*SCALE;
    const float* grow = G + (size_t)bi*NCAND;
    float best2 = -1e30f; int b2 = 0x7fffffff;
    #pragma unroll
    for (int i=0;i<43;++i){
        int c = i*64 + lane;
        float v = (c < NCAND) ? fmaf(-rs, grow[c], s[i]) : -1e30f;
        if (v > best2){ best2 = v; b2 = c; }
    }
    #pragma unroll
    for (int off=32; off; off>>=1){
        float v2 = __shfl_xor(best2, off);
        int   i2 = __shfl_xor(b2, off);
        if (v2 > best2 || (v2 == best2 && i2 < b2)){ best2 = v2; b2 = i2; }
    }
    if (lane == 0){
        float den2   = G[(size_t)b2*NCAND + b2];
        float ratio2 = best2 / (SCALE*den2);
        int ei = b2 / NAZI, ai = b2 - ei*NAZI;
        out_doa[(size_t)row*4 + 1] = ele_c[ei];
        out_doa[(size_t)row*4 + 3] = azi_c[ai];
        out_vad[(size_t)row*2 + 1] = ratio2;
    }
}

// ---------- launch ----------
extern "C" void kernel_launch(void* const* d_in, const int* in_sizes, int n_in,
                              void* d_out, int out_size, void* d_ws, size_t ws_size,
                              hipStream_t stream)
{
    const float* ipd   = (const float*)d_in[0];   // [8192,1024]
    const float* tmpl  = (const float*)d_in[1];   // [2701,1024]
    const float* ele_c = (const float*)d_in[2];
    const float* azi_c = (const float*)d_in[3];

    float* out     = (float*)d_out;
    float* out_doa = out;                                       // [8192,2,2]
    float* out_vad = out + (size_t)MROWS*4;                     // [8192,2]
    float* out_ss  = out + (size_t)MROWS*4 + (size_t)MROWS*2;   // [8192,2701]

    char*  ws = (char*)d_ws;
    float* G  = (float*)ws;

    dim3 blk256(256);

    if (ws_size >= WS_FAST) {
        f16* A2 = (f16*)(ws + A2_OFF);
        f16* B2 = (f16*)(ws + B2_OFF);

        hipLaunchKernelGGL(split_interleave, dim3(MROWS*128/256), blk256, 0, stream,
                           ipd, A2, MROWS, MROWS);
        hipLaunchKernelGGL(split_interleave, dim3(NPAD*128/256), blk256, 0, stream,
                           tmpl, B2, NCAND, NPAD);

        // pred_ss: [8192 x 2701]
        hipLaunchKernelGGL((gemm_limb<0>), dim3(22, 32), dim3(512), 0, stream,
                           A2, B2, out_ss, MROWS, NCAND, SCALE);
        // Gram (symmetric, triangular grid): [2701 x 2701]
        hipLaunchKernelGGL((gemm_limb<1>), dim3(132), dim3(512), 0, stream,
                           B2, B2, G, NCAND, NCAND, 1.0f);
    } else {
        dim3 g1((NCAND + TILE - 1)/TILE, MROWS/TILE);
        hipLaunchKernelGGL(sgemm_nt_kernel, g1, blk256, 0, stream,
                           ipd, tmpl, out_ss, MROWS, NCAND, SCALE);
        dim3 g2((NCAND + TILE - 1)/TILE, (NCAND + TILE - 1)/TILE);
        hipLaunchKernelGGL(sgemm_nt_kernel, g2, blk256, 0, stream,
                           tmpl, tmpl, G, NCAND, NCAND, 1.0f);
    }

    hipLaunchKernelGGL(argmax_fused, dim3(MROWS/4), blk256, 0, stream,
                       out_ss, G, ele_c, azi_c, out_doa, out_vad);
}

// Round 7
// 333.415 us; speedup vs baseline: 1.1557x; 1.0781x over previous
//
#include <hip/hip_runtime.h>
#include <math.h>

typedef _Float16 f16;
typedef __attribute__((ext_vector_type(8))) _Float16 f16x8;
typedef __attribute__((ext_vector_type(4))) float    f32x4;
typedef __attribute__((address_space(3))) unsigned int       as3u32;
typedef const __attribute__((address_space(1))) unsigned int as1u32;

constexpr int NB=16, NT=512, NF=256, NMIC=4, NELE=37, NAZI=73;
constexpr int MROWS = NB*NT;     // 8192
constexpr int KDIM  = NF*NMIC;   // 1024
constexpr int NCAND = NELE*NAZI; // 2701
constexpr int NPAD  = 2816;      // padded candidate rows (22*128)
constexpr float SCALE = 2.0f / (float)KDIM;

// unified grid geometry
constexpr int NBT_ROW = MROWS/128;            // 64
constexpr int NBT_COL = NPAD/128;             // 22
constexpr int NBLK_SS = NBT_ROW*NBT_COL;      // 1408
constexpr int NBLK_GR = NBT_COL*(NBT_COL+1)/2; // 253 (triangular incl. diagonal)
constexpr int NBLK    = NBLK_SS + NBLK_GR;    // 1661

constexpr size_t align256(size_t x){ return (x + 255) & ~(size_t)255; }
constexpr size_t G_BYTES = (size_t)NCAND*NCAND*4;          // 29.18 MB
constexpr size_t AHI_OFF = align256(G_BYTES);
constexpr size_t A_BYTES = (size_t)MROWS*KDIM*2;           // 16.78 MB
constexpr size_t ALO_OFF = AHI_OFF + A_BYTES;
constexpr size_t BHI_OFF = ALO_OFF + A_BYTES;
constexpr size_t B_BYTES = (size_t)NPAD*KDIM*2;            // 5.77 MB
constexpr size_t BLO_OFF = BHI_OFF + B_BYTES;
constexpr size_t WS_FAST = BLO_OFF + B_BYTES;              // ~63.9 MB

// ---------------- pre-pass: split f32 -> (hi, lo*2^11) f16 limbs ----------------
__global__ __launch_bounds__(256)
void split_kernel(const float* __restrict__ src, f16* __restrict__ hi, f16* __restrict__ lo,
                  long nsrc, long ntot)
{
    long i = ((long)blockIdx.x*256 + threadIdx.x)*8;
    if (i >= ntot) return;
    f16x8 h, l;
    if (i < nsrc) {
        float4 x0 = *(const float4*)(src + i);
        float4 x1 = *(const float4*)(src + i + 4);
        float xs[8] = {x0.x,x0.y,x0.z,x0.w,x1.x,x1.y,x1.z,x1.w};
        #pragma unroll
        for (int j=0;j<8;++j){
            f16 hh = (f16)xs[j];
            float r = (xs[j] - (float)hh) * 2048.0f;
            h[j] = hh; l[j] = (f16)r;
        }
    } else {
        #pragma unroll
        for (int j=0;j<8;++j){ h[j]=(f16)0.0f; l[j]=(f16)0.0f; }
    }
    *(f16x8*)(hi + i) = h;
    *(f16x8*)(lo + i) = l;
}

// ---------- unified split-f16 MFMA GEMM (m97 2-barrier structure, 8 waves) ----------
// Tile 128x128, BK=64 f32-k. blocks [0,1408): pred_ss = (A·B^T)*SCALE -> C_ss.
// blocks [1408,1661): Gram triangular = (B·B^T) -> G, mirror-write off-diagonal.
// LDS 64 KB -> 2 blocks/CU; 8 waves (2 row x 4 col), wave-tile 64x32 (round-3 proven shape).
__global__ __launch_bounds__(512, 4)
void gemm_unified(const f16* __restrict__ Ahi, const f16* __restrict__ Alo,
                  const f16* __restrict__ Bhi, const f16* __restrict__ Blo,
                  float* __restrict__ C_ss, float* __restrict__ G)
{
    __shared__ __align__(16) f16 sAhi[128*64];   // 16 KB each
    __shared__ __align__(16) f16 sAlo[128*64];
    __shared__ __align__(16) f16 sBhi[128*64];
    __shared__ __align__(16) f16 sBlo[128*64];

    const int tid  = threadIdx.x;
    const int wid  = tid >> 6;
    const int lane = tid & 63;
    const int wr   = wid >> 2;   // 0..1 : 64-row band
    const int wc   = wid & 3;    // 0..3 : 32-col band

    // bijective XCD swizzle (m204) over the full 1D grid
    const int nwg  = gridDim.x;
    const int orig = blockIdx.x;
    const int q = nwg >> 3, r8 = nwg & 7;
    const int xcd = orig & 7, inner = orig >> 3;
    const int wg = (xcd < r8 ? xcd*(q+1) : r8*(q+1) + (xcd-r8)*q) + inner;

    // role
    const f16 *pAhi, *pAlo, *pBhi, *pBlo;
    float* Cp; int row0, col0, Ml; float scale; bool mirror;
    if (wg < NBLK_SS) {
        row0 = (wg / NBT_COL) * 128;
        col0 = (wg % NBT_COL) * 128;
        pAhi = Ahi; pAlo = Alo; pBhi = Bhi; pBlo = Blo;
        Cp = C_ss; Ml = MROWS; scale = SCALE; mirror = false;
    } else {
        int t = wg - NBLK_SS, i = 0;
        #pragma unroll 1
        for (; i < NBT_COL; ++i){ int cnt = NBT_COL - i; if (t < cnt) break; t -= cnt; }
        row0 = i * 128;
        col0 = (i + t) * 128;
        pAhi = Bhi; pAlo = Blo; pBhi = Bhi; pBlo = Blo;
        Cp = G; Ml = NCAND; scale = 1.0f; mirror = (t > 0);   // diagonal block: no mirror (deterministic)
    }

    // staging lane geometry: chunk = 8 rows x 128 B (64 f16); granule swizzle g ^= row&7
    const int lr8 = lane >> 3;        // 0..7 row-in-chunk
    const int lg  = lane & 7;         // dest granule
    const int sg  = lg ^ lr8;         // pre-swizzled source granule

    // ds_read offsets (f16 units), same involution on read
    int aoff[4][2], boff[2][2];
    #pragma unroll
    for (int fi=0; fi<4; ++fi){
        int ra = wr*64 + fi*16 + (lane & 15);
        #pragma unroll
        for (int ks=0; ks<2; ++ks){
            int g = ks*4 + (lane >> 4);
            aoff[fi][ks] = ra*64 + ((g ^ (ra & 7)) * 8);
        }
    }
    #pragma unroll
    for (int fj=0; fj<2; ++fj){
        int rb = wc*32 + fj*16 + (lane & 15);
        #pragma unroll
        for (int ks=0; ks<2; ++ks){
            int g = ks*4 + (lane >> 4);
            boff[fj][ks] = rb*64 + ((g ^ (rb & 7)) * 8);
        }
    }

    f32x4 acc0[4][2], acc1[4][2];
    #pragma unroll
    for (int i=0;i<4;++i)
        #pragma unroll
        for (int j=0;j<2;++j){
            acc0[i][j] = (f32x4){0.f,0.f,0.f,0.f};
            acc1[i][j] = (f32x4){0.f,0.f,0.f,0.f};
        }

    for (int k0 = 0; k0 < KDIM; k0 += 64) {
        // ---- stage tiles: 16 chunks each array; wave handles chunks j*8+wid (j=0,1)
        #pragma unroll
        for (int j=0; j<2; ++j){
            int c_ = j*8 + wid;
            long soA = (long)(row0 + c_*8 + lr8)*KDIM + k0 + sg*8;
            long soB = (long)(col0 + c_*8 + lr8)*KDIM + k0 + sg*8;
            __builtin_amdgcn_global_load_lds((as1u32*)(pAhi + soA),
                (as3u32*)(sAhi + (size_t)c_*512), 16, 0, 0);
            __builtin_amdgcn_global_load_lds((as1u32*)(pAlo + soA),
                (as3u32*)(sAlo + (size_t)c_*512), 16, 0, 0);
            __builtin_amdgcn_global_load_lds((as1u32*)(pBhi + soB),
                (as3u32*)(sBhi + (size_t)c_*512), 16, 0, 0);
            __builtin_amdgcn_global_load_lds((as1u32*)(pBlo + soB),
                (as3u32*)(sBlo + (size_t)c_*512), 16, 0, 0);
        }
        __syncthreads();   // drains vmcnt; tiles visible

        #pragma unroll
        for (int ks=0; ks<2; ++ks){
            f16x8 ah[4], al[4], bh[2], bl[2];
            #pragma unroll
            for (int fi=0; fi<4; ++fi){
                ah[fi] = *(const f16x8*)(sAhi + aoff[fi][ks]);
                al[fi] = *(const f16x8*)(sAlo + aoff[fi][ks]);
            }
            #pragma unroll
            for (int fj=0; fj<2; ++fj){
                bh[fj] = *(const f16x8*)(sBhi + boff[fj][ks]);
                bl[fj] = *(const f16x8*)(sBlo + boff[fj][ks]);
            }
            #pragma unroll
            for (int fi=0; fi<4; ++fi)
                #pragma unroll
                for (int fj=0; fj<2; ++fj){
                    acc0[fi][fj] = __builtin_amdgcn_mfma_f32_16x16x32_f16(ah[fi], bh[fj], acc0[fi][fj], 0,0,0);
                    acc1[fi][fj] = __builtin_amdgcn_mfma_f32_16x16x32_f16(ah[fi], bl[fj], acc1[fi][fj], 0,0,0);
                    acc1[fi][fj] = __builtin_amdgcn_mfma_f32_16x16x32_f16(al[fi], bh[fj], acc1[fi][fj], 0,0,0);
                }
        }
        __syncthreads();   // reads done before next-iter staging overwrites
    }

    // epilogue: C/D layout col=lane&15, row=(lane>>4)*4+e; stride NCAND for both outputs
    const float inv2048 = 1.0f/2048.0f;
    #pragma unroll
    for (int fi=0; fi<4; ++fi){
        #pragma unroll
        for (int fj=0; fj<2; ++fj){
            int c = col0 + wc*32 + fj*16 + (lane & 15);
            #pragma unroll
            for (int e=0; e<4; ++e){
                int r = row0 + wr*64 + fi*16 + (lane >> 4)*4 + e;
                if (r < Ml && c < NCAND){
                    float v = (acc0[fi][fj][e] + acc1[fi][fj][e]*inv2048)*scale;
                    Cp[(size_t)r*NCAND + c] = v;
                    if (mirror) Cp[(size_t)c*NCAND + r] = v;
                }
            }
        }
    }
}

// ---------- fallback f32 SGEMM (round-1, known-good) ----------
#define TILE 64
#define BKK  16
#define LDSP 68
__global__ __launch_bounds__(256)
void sgemm_nt_kernel(const float* __restrict__ A, const float* __restrict__ B,
                     float* __restrict__ C, int M, int N, float scale)
{
    __shared__ __align__(16) float As[BKK][LDSP];
    __shared__ __align__(16) float Bs[BKK][LDSP];
    const int tid = threadIdx.x;
    const int tx = tid & 15, ty = tid >> 4;
    const int row0 = blockIdx.y*TILE, col0 = blockIdx.x*TILE;
    const int lm = tid >> 2, lk0 = (tid & 3)*4;
    const int ar = row0 + lm, br = col0 + lm;
    const bool av = (ar < M), bv = (br < N);
    const float* aptr = A + (size_t)(av ? ar : 0)*KDIM + lk0;
    const float* bptr = B + (size_t)(bv ? br : 0)*KDIM + lk0;
    float acc[4][4] = {};
    for (int k0 = 0; k0 < KDIM; k0 += BKK) {
        float4 a4 = av ? *(const float4*)(aptr + k0) : make_float4(0,0,0,0);
        float4 b4 = bv ? *(const float4*)(bptr + k0) : make_float4(0,0,0,0);
        __syncthreads();
        As[lk0+0][lm]=a4.x; As[lk0+1][lm]=a4.y; As[lk0+2][lm]=a4.z; As[lk0+3][lm]=a4.w;
        Bs[lk0+0][lm]=b4.x; Bs[lk0+1][lm]=b4.y; Bs[lk0+2][lm]=b4.z; Bs[lk0+3][lm]=b4.w;
        __syncthreads();
        #pragma unroll
        for (int k=0;k<BKK;++k){
            float4 av4 = *(const float4*)(&As[k][ty*4]);
            float4 bv4 = *(const float4*)(&Bs[k][tx*4]);
            float am[4]={av4.x,av4.y,av4.z,av4.w};
            float bm[4]={bv4.x,bv4.y,bv4.z,bv4.w};
            #pragma unroll
            for (int i=0;i<4;++i)
                #pragma unroll
                for (int j=0;j<4;++j)
                    acc[i][j] = fmaf(am[i], bm[j], acc[i][j]);
        }
    }
    #pragma unroll
    for (int i=0;i<4;++i){
        int r = row0 + ty*4 + i;
        if (r >= M) continue;
        #pragma unroll
        for (int j=0;j<4;++j){
            int c = col0 + tx*4 + j;
            if (c < N) C[(size_t)r*N + c] = acc[i][j]*scale;
        }
    }
}

// ---------- fused IDL argmax: both iterations, ss row kept in registers ----------
__global__ __launch_bounds__(256)
void argmax_fused(const float* __restrict__ ss, const float* __restrict__ G,
                  const float* __restrict__ ele_c, const float* __restrict__ azi_c,
                  float* __restrict__ out_doa, float* __restrict__ out_vad)
{
    const int row  = blockIdx.x*4 + (threadIdx.x >> 6);
    const int lane = threadIdx.x & 63;
    const float* srow = ss + (size_t)row*NCAND;

    float s[43];
    #pragma unroll
    for (int i=0;i<43;++i){
        int c = i*64 + lane;
        s[i] = (c < NCAND) ? srow[c] : -1e30f;
    }

    // ---- iteration 1
    float best = -1e30f; int bi = 0x7fffffff;
    #pragma unroll
    for (int i=0;i<43;++i){
        int c = i*64 + lane;
        if (s[i] > best){ best = s[i]; bi = c; }
    }
    #pragma unroll
    for (int off=32; off; off>>=1){
        float v2 = __shfl_xor(best, off);
        int   i2 = __shfl_xor(bi, off);
        if (v2 > best || (v2 == best && i2 < bi)){ best = v2; bi = i2; }
    }
    float den   = G[(size_t)bi*NCAND + bi];
    float ratio = best / (SCALE*den);
    if (lane == 0){
        int ei = bi / NAZI, ai = bi - ei*NAZI;
        out_doa[(size_t)row*4 + 0] = ele_c[ei];
        out_doa[(size_t)row*4 + 2] = azi_c[ai];
        out_vad[(size_t)row*2 + 0] = ratio;
    }

    // ---- iteration 2: scores2 = s - ratio*SCALE*G[bi, :]
    const float rs = ratio*SCALE;
    const float* grow = G + (size_t)bi*NCAND;
    float best2 = -1e30f; int b2 = 0x7fffffff;
    #pragma unroll
    for (int i=0;i<43;++i){
        int c = i*64 + lane;
        float v = (c < NCAND) ? fmaf(-rs, grow[c], s[i]) : -1e30f;
        if (v > best2){ best2 = v; b2 = c; }
    }
    #pragma unroll
    for (int off=32; off; off>>=1){
        float v2 = __shfl_xor(best2, off);
        int   i2 = __shfl_xor(b2, off);
        if (v2 > best2 || (v2 == best2 && i2 < b2)){ best2 = v2; b2 = i2; }
    }
    if (lane == 0){
        float den2   = G[(size_t)b2*NCAND + b2];
        float ratio2 = best2 / (SCALE*den2);
        int ei = b2 / NAZI, ai = b2 - ei*NAZI;
        out_doa[(size_t)row*4 + 1] = ele_c[ei];
        out_doa[(size_t)row*4 + 3] = azi_c[ai];
        out_vad[(size_t)row*2 + 1] = ratio2;
    }
}

// ---------- launch ----------
extern "C" void kernel_launch(void* const* d_in, const int* in_sizes, int n_in,
                              void* d_out, int out_size, void* d_ws, size_t ws_size,
                              hipStream_t stream)
{
    const float* ipd   = (const float*)d_in[0];   // [8192,1024]
    const float* tmpl  = (const float*)d_in[1];   // [2701,1024]
    const float* ele_c = (const float*)d_in[2];
    const float* azi_c = (const float*)d_in[3];

    float* out     = (float*)d_out;
    float* out_doa = out;                                       // [8192,2,2]
    float* out_vad = out + (size_t)MROWS*4;                     // [8192,2]
    float* out_ss  = out + (size_t)MROWS*4 + (size_t)MROWS*2;   // [8192,2701]

    char*  ws = (char*)d_ws;
    float* G  = (float*)ws;

    dim3 blk256(256);

    if (ws_size >= WS_FAST) {
        f16* Ahi = (f16*)(ws + AHI_OFF);
        f16* Alo = (f16*)(ws + ALO_OFF);
        f16* Bhi = (f16*)(ws + BHI_OFF);
        f16* Blo = (f16*)(ws + BLO_OFF);

        long nA = (long)MROWS*KDIM;
        long nBs = (long)NCAND*KDIM, nBt = (long)NPAD*KDIM;
        hipLaunchKernelGGL(split_kernel, dim3((unsigned)(nA/2048)), blk256, 0, stream,
                           ipd, Ahi, Alo, nA, nA);
        hipLaunchKernelGGL(split_kernel, dim3((unsigned)(nBt/2048)), blk256, 0, stream,
                           tmpl, Bhi, Blo, nBs, nBt);

        // pred_ss + triangular Gram in ONE launch (Gram blocks fill the tail)
        hipLaunchKernelGGL(gemm_unified, dim3(NBLK), dim3(512), 0, stream,
                           Ahi, Alo, Bhi, Blo, out_ss, G);
    } else {
        dim3 g1((NCAND + TILE - 1)/TILE, MROWS/TILE);
        hipLaunchKernelGGL(sgemm_nt_kernel, g1, blk256, 0, stream,
                           ipd, tmpl, out_ss, MROWS, NCAND, SCALE);
        dim3 g2((NCAND + TILE - 1)/TILE, (NCAND + TILE - 1)/TILE);
        hipLaunchKernelGGL(sgemm_nt_kernel, g2, blk256, 0, stream,
                           tmpl, tmpl, G, NCAND, NCAND, 1.0f);
    }

    hipLaunchKernelGGL(argmax_fused, dim3(MROWS/4), blk256, 0, stream,
                       out_ss, G, ele_c, azi_c, out_doa, out_vad);
}